// Round 1
// baseline (164.097 us; speedup 1.0000x reference)
//
#include <hip/hip_runtime.h>

// EndPointSpline: Q=2048 queries, B=128 batch cols, T=128 knot times, D=512 feat
// out[b,q,d] = xt[left,b,d] + (xt[left+1,b,d]-xt[left,b,d]) * (q - t[left,b]) / (t[left+1,b]-t[left,b]+1e-10)
// where left = clip(searchsorted(t[1:,b], query_t[q], 'left'), 0, T-2)
// xt[0]=x0[b], xt[i]=knots[b,i-1], xt[T-1]=x1[b]

#define QN 2048
#define BN 128
#define TN 128
#define DN 512

typedef float f4 __attribute__((ext_vector_type(4)));

__global__ __launch_bounds__(256) void EndPointSpline_kernel(
    const float* __restrict__ query_t,   // [Q]
    const float* __restrict__ knots,     // [B, T-2, D]
    const float* __restrict__ x0,        // [B, D]  (leading 1 dim dropped)
    const float* __restrict__ x1,        // [B, D]
    const float* __restrict__ t,         // [T, B]
    float* __restrict__ out)             // [B, Q, D]
{
    const int b    = blockIdx.y;
    const int grp  = threadIdx.x >> 7;          // which of the 2 queries
    const int lane = threadIdx.x & 127;         // 0..127, one float4 each
    const int q    = (blockIdx.x << 1) + grp;

    const float qt = query_t[q];

    // searchsorted(t[1:], qt, side='left') == count of t[1..T-1] < qt
    // binary search: smallest i in [0,127) with t[i+1] >= qt (127 if none)
    int lo = 0, hi = TN - 1;
    while (lo < hi) {
        const int mid = (lo + hi) >> 1;
        const float tm = t[(mid + 1) * BN + b];
        if (tm < qt) lo = mid + 1; else hi = mid;
    }
    const int left = (lo > TN - 2) ? (TN - 2) : lo;   // clip to [0, T-2]

    const float tl = t[left * BN + b];
    const float tr = t[(left + 1) * BN + b];
    const float scale = (qt - tl) / (tr - tl + 1e-10f);

    // xt row pointers (branches are uniform per wave: left is per-query)
    const float* row0 = (left == 0)
        ? (x0 + (size_t)b * DN)
        : (knots + ((size_t)b * (TN - 2) + (left - 1)) * DN);
    const float* row1 = (left == TN - 2)
        ? (x1 + (size_t)b * DN)
        : (knots + ((size_t)b * (TN - 2) + left) * DN);

    const int d = lane << 2;                    // 0..508 step 4
    const f4 a = *(const f4*)(row0 + d);
    const f4 c = *(const f4*)(row1 + d);
    f4 r;
    r.x = fmaf(c.x - a.x, scale, a.x);
    r.y = fmaf(c.y - a.y, scale, a.y);
    r.z = fmaf(c.z - a.z, scale, a.z);
    r.w = fmaf(c.w - a.w, scale, a.w);

    float* op = out + ((size_t)b * QN + q) * DN + d;
    __builtin_nontemporal_store(r, (f4*)op);
}

extern "C" void kernel_launch(void* const* d_in, const int* in_sizes, int n_in,
                              void* d_out, int out_size, void* d_ws, size_t ws_size,
                              hipStream_t stream) {
    const float* query_t = (const float*)d_in[0];
    const float* knots   = (const float*)d_in[1];
    const float* x0      = (const float*)d_in[2];
    const float* x1      = (const float*)d_in[3];
    const float* t       = (const float*)d_in[4];
    float* out           = (float*)d_out;

    dim3 grid(QN / 2, BN);   // x fastest => consecutive blocks share b => L2 reuse of xt[:,b,:]
    dim3 block(256);
    EndPointSpline_kernel<<<grid, block, 0, stream>>>(query_t, knots, x0, x1, t, out);
}

// Round 2
// 112.836 us; speedup vs baseline: 1.4543x; 1.4543x over previous
//
#include <hip/hip_runtime.h>

// EndPointSpline: Q=2048 queries, B=128 batch cols, T=128 knot times, D=512 feat
// out[b,q,d] = xt[left,b,d] + (xt[left+1,b,d]-xt[left,b,d]) * (qt - t[left,b]) / (t[left+1,b]-t[left,b]+1e-10)
// left = clip(searchsorted(t[1:,b], qt, 'left'), 0, T-2)
// xt[0]=x0[b], xt[i]=knots[b,i-1], xt[T-1]=x1[b]
//
// Structure (R1): block = 16 queries x 16 lanes. Each thread owns ONE query
// (binary search once per thread, parallel, no LDS), then loops 8x over D
// issuing 2 loads + 1 nontemporal store per iter -> 32 KiB of stores per
// block, 8x the streaming-per-search of R0 (which was store-starved at 164us).

#define QN 2048
#define BN 128
#define TN 128
#define DN 512

#define QPB 16   // queries per block
#define LPQ 16   // lanes per query
#define DITER (DN / (LPQ * 4))   // 8 d-iterations, f4 each

typedef float f4 __attribute__((ext_vector_type(4)));

__global__ __launch_bounds__(256) void EndPointSpline_kernel(
    const float* __restrict__ query_t,   // [Q]
    const float* __restrict__ knots,     // [B, T-2, D]
    const float* __restrict__ x0,        // [B, D]
    const float* __restrict__ x1,        // [B, D]
    const float* __restrict__ t,         // [T, B]
    float* __restrict__ out)             // [B, Q, D]
{
    const int b    = blockIdx.y;
    const int tq   = threadIdx.x >> 4;          // 0..15 : which query in block
    const int lane = threadIdx.x & 15;          // 0..15 : f4 slot within row chunk
    const int q    = blockIdx.x * QPB + tq;

    const float qt = query_t[q];

    // smallest i in [0,127) with t[i+1] >= qt (127 if none) == searchsorted(t[1:], qt)
    int lo = 0, hi = TN - 1;
    while (lo < hi) {
        const int mid = (lo + hi) >> 1;
        const float tm = t[(mid + 1) * BN + b];
        if (tm < qt) lo = mid + 1; else hi = mid;
    }
    const int left = (lo > TN - 2) ? (TN - 2) : lo;   // clip to [0, T-2]

    const float tl = t[left * BN + b];
    const float tr = t[(left + 1) * BN + b];
    const float scale = (qt - tl) / (tr - tl + 1e-10f);

    const float* row0 = (left == 0)
        ? (x0 + (size_t)b * DN)
        : (knots + ((size_t)b * (TN - 2) + (left - 1)) * DN);
    const float* row1 = (left == TN - 2)
        ? (x1 + (size_t)b * DN)
        : (knots + ((size_t)b * (TN - 2) + left) * DN);

    float* orow = out + ((size_t)b * QN + q) * DN;

    const int d0 = lane << 2;                   // 0..60 step 4
#pragma unroll
    for (int di = 0; di < DITER; ++di) {
        const int d = d0 + di * (LPQ * 4);      // stride 64 floats
        const f4 a = *(const f4*)(row0 + d);
        const f4 c = *(const f4*)(row1 + d);
        f4 r;
        r.x = fmaf(c.x - a.x, scale, a.x);
        r.y = fmaf(c.y - a.y, scale, a.y);
        r.z = fmaf(c.z - a.z, scale, a.z);
        r.w = fmaf(c.w - a.w, scale, a.w);
        __builtin_nontemporal_store(r, (f4*)(orow + d));
    }
}

extern "C" void kernel_launch(void* const* d_in, const int* in_sizes, int n_in,
                              void* d_out, int out_size, void* d_ws, size_t ws_size,
                              hipStream_t stream) {
    const float* query_t = (const float*)d_in[0];
    const float* knots   = (const float*)d_in[1];
    const float* x0      = (const float*)d_in[2];
    const float* x1      = (const float*)d_in[3];
    const float* t       = (const float*)d_in[4];
    float* out           = (float*)d_out;

    dim3 grid(QN / QPB, BN);   // x fastest => consecutive blocks share b => L2 reuse
    dim3 block(QPB * LPQ);
    EndPointSpline_kernel<<<grid, block, 0, stream>>>(query_t, knots, x0, x1, t, out);
}

// Round 3
// 99.605 us; speedup vs baseline: 1.6475x; 1.1328x over previous
//
#include <hip/hip_runtime.h>

// EndPointSpline: Q=2048 queries, B=128 batch cols, T=128 knot times, D=512 feat
// out[b,q,d] = xt[left,b,d] + (xt[left+1,b,d]-xt[left,b,d]) * (qt - t[left,b]) / (t[left+1,b]-t[left,b]+1e-10)
// left = clip(searchsorted(t[1:,b], qt, 'left'), 0, T-2)
// xt[0]=x0[b], xt[i]=knots[b,i-1], xt[T-1]=x1[b]
//
// R1: block = 16 queries x 16 lanes, 8 d-iters of f4 -> 112.8us.
// R2: XCD-aware block mapping. R1's (x=qchunk fastest) round-robins one b's
// 128 blocks across all 8 XCD-private L2s -> each XCD refetches the 256KiB
// xt slab: reads 8x32MB=256MB instead of 32MB. Map all q-chunks of a given b
// to ONE XCD (b%8 == bid%8): each XCD serves 16 slabs = 4MiB (L2-sized),
// walked sequentially. Cuts HBM reads ~256MB -> ~40MB.

#define QN 2048
#define BN 128
#define TN 128
#define DN 512

#define QPB 16   // queries per block
#define LPQ 16   // lanes per query
#define DITER (DN / (LPQ * 4))   // 8 d-iterations, f4 each

typedef float f4 __attribute__((ext_vector_type(4)));

__global__ __launch_bounds__(256) void EndPointSpline_kernel(
    const float* __restrict__ query_t,   // [Q]
    const float* __restrict__ knots,     // [B, T-2, D]
    const float* __restrict__ x0,        // [B, D]
    const float* __restrict__ x1,        // [B, D]
    const float* __restrict__ t,         // [T, B]
    float* __restrict__ out)             // [B, Q, D]
{
    // XCD-aware decode: dispatch round-robins bid%8 across XCDs.
    const int bid    = blockIdx.x;
    const int xcd    = bid & 7;
    const int slot   = bid >> 3;                 // 0..2047 within this XCD
    const int b      = xcd + ((slot >> 7) << 3); // 16 b's per XCD, sequential
    const int qchunk = slot & 127;               // q-chunk varies fastest

    const int tq   = threadIdx.x >> 4;          // 0..15 : which query in block
    const int lane = threadIdx.x & 15;          // 0..15 : f4 slot within row
    const int q    = qchunk * QPB + tq;

    const float qt = query_t[q];

    // smallest i in [0,127) with t[i+1] >= qt (127 if none) == searchsorted(t[1:], qt)
    int lo = 0, hi = TN - 1;
    while (lo < hi) {
        const int mid = (lo + hi) >> 1;
        const float tm = t[(mid + 1) * BN + b];
        if (tm < qt) lo = mid + 1; else hi = mid;
    }
    const int left = (lo > TN - 2) ? (TN - 2) : lo;   // clip to [0, T-2]

    const float tl = t[left * BN + b];
    const float tr = t[(left + 1) * BN + b];
    const float scale = (qt - tl) / (tr - tl + 1e-10f);

    const float* row0 = (left == 0)
        ? (x0 + (size_t)b * DN)
        : (knots + ((size_t)b * (TN - 2) + (left - 1)) * DN);
    const float* row1 = (left == TN - 2)
        ? (x1 + (size_t)b * DN)
        : (knots + ((size_t)b * (TN - 2) + left) * DN);

    float* orow = out + ((size_t)b * QN + q) * DN;

    const int d0 = lane << 2;                   // 0..60 step 4
#pragma unroll
    for (int di = 0; di < DITER; ++di) {
        const int d = d0 + di * (LPQ * 4);      // stride 64 floats
        const f4 a = *(const f4*)(row0 + d);
        const f4 c = *(const f4*)(row1 + d);
        f4 r;
        r.x = fmaf(c.x - a.x, scale, a.x);
        r.y = fmaf(c.y - a.y, scale, a.y);
        r.z = fmaf(c.z - a.z, scale, a.z);
        r.w = fmaf(c.w - a.w, scale, a.w);
        __builtin_nontemporal_store(r, (f4*)(orow + d));
    }
}

extern "C" void kernel_launch(void* const* d_in, const int* in_sizes, int n_in,
                              void* d_out, int out_size, void* d_ws, size_t ws_size,
                              hipStream_t stream) {
    const float* query_t = (const float*)d_in[0];
    const float* knots   = (const float*)d_in[1];
    const float* x0      = (const float*)d_in[2];
    const float* x1      = (const float*)d_in[3];
    const float* t       = (const float*)d_in[4];
    float* out           = (float*)d_out;

    dim3 grid((QN / QPB) * BN);   // 16384 blocks, 1D, XCD-decoded in-kernel
    dim3 block(QPB * LPQ);
    EndPointSpline_kernel<<<grid, block, 0, stream>>>(query_t, knots, x0, x1, t, out);
}

// Round 4
// 98.155 us; speedup vs baseline: 1.6718x; 1.0148x over previous
//
#include <hip/hip_runtime.h>

// EndPointSpline: Q=2048 queries, B=128 batch cols, T=128 knot times, D=512 feat
// out[b,q,d] = xt[left,b,d] + (xt[left+1,b,d]-xt[left,b,d]) * (qt - t[left,b]) / (t[left+1,b]-t[left,b]+1e-10)
// left = clip(searchsorted(t[1:,b], qt, 'left'), 0, T-2)
// xt[0]=x0[b], xt[i]=knots[b,i-1], xt[T-1]=x1[b]
//
// R1: block = 16q x 16 lanes, 8 d-iters         -> 112.8us
// R2: + XCD-aware mapping (all q of a b on 1 XCD) -> 99.6us
// R3: amortize search 2x more: block = 32q x 8 lanes, 16 d-iters
//     (256B stored per binary search instead of 128B; searches 4.2M->2.1M)

#define QN 2048
#define BN 128
#define TN 128
#define DN 512

#define QPB 32   // queries per block
#define LPQ 8    // lanes per query
#define DITER (DN / (LPQ * 4))   // 16 d-iterations, f4 each

typedef float f4 __attribute__((ext_vector_type(4)));

__global__ __launch_bounds__(256) void EndPointSpline_kernel(
    const float* __restrict__ query_t,   // [Q]
    const float* __restrict__ knots,     // [B, T-2, D]
    const float* __restrict__ x0,        // [B, D]
    const float* __restrict__ x1,        // [B, D]
    const float* __restrict__ t,         // [T, B]
    float* __restrict__ out)             // [B, Q, D]
{
    // XCD-aware decode: dispatch round-robins bid%8 across the 8 XCDs.
    // Per XCD: 1024 slots = 16 b-slabs x 64 qchunks (qchunk fastest).
    const int bid    = blockIdx.x;
    const int xcd    = bid & 7;
    const int slot   = bid >> 3;                 // 0..1023 within this XCD
    const int b      = xcd + ((slot >> 6) << 3); // 16 b's per XCD
    const int qchunk = slot & 63;                // varies fastest

    const int tq   = threadIdx.x >> 3;          // 0..31 : which query in block
    const int lane = threadIdx.x & 7;           // 0..7  : f4 slot within row
    const int q    = qchunk * QPB + tq;

    const float qt = query_t[q];

    // smallest i in [0,127) with t[i+1] >= qt (127 if none) == searchsorted(t[1:], qt)
    int lo = 0, hi = TN - 1;
    while (lo < hi) {
        const int mid = (lo + hi) >> 1;
        const float tm = t[(mid + 1) * BN + b];
        if (tm < qt) lo = mid + 1; else hi = mid;
    }
    const int left = (lo > TN - 2) ? (TN - 2) : lo;   // clip to [0, T-2]

    const float tl = t[left * BN + b];
    const float tr = t[(left + 1) * BN + b];
    const float scale = (qt - tl) / (tr - tl + 1e-10f);

    const float* row0 = (left == 0)
        ? (x0 + (size_t)b * DN)
        : (knots + ((size_t)b * (TN - 2) + (left - 1)) * DN);
    const float* row1 = (left == TN - 2)
        ? (x1 + (size_t)b * DN)
        : (knots + ((size_t)b * (TN - 2) + left) * DN);

    float* orow = out + ((size_t)b * QN + q) * DN;

    const int d0 = lane << 2;                   // 0..28 step 4
#pragma unroll
    for (int di = 0; di < DITER; ++di) {
        const int d = d0 + di * (LPQ * 4);      // stride 32 floats
        const f4 a = *(const f4*)(row0 + d);
        const f4 c = *(const f4*)(row1 + d);
        f4 r;
        r.x = fmaf(c.x - a.x, scale, a.x);
        r.y = fmaf(c.y - a.y, scale, a.y);
        r.z = fmaf(c.z - a.z, scale, a.z);
        r.w = fmaf(c.w - a.w, scale, a.w);
        __builtin_nontemporal_store(r, (f4*)(orow + d));
    }
}

extern "C" void kernel_launch(void* const* d_in, const int* in_sizes, int n_in,
                              void* d_out, int out_size, void* d_ws, size_t ws_size,
                              hipStream_t stream) {
    const float* query_t = (const float*)d_in[0];
    const float* knots   = (const float*)d_in[1];
    const float* x0      = (const float*)d_in[2];
    const float* x1      = (const float*)d_in[3];
    const float* t       = (const float*)d_in[4];
    float* out           = (float*)d_out;

    dim3 grid((QN / QPB) * BN);   // 8192 blocks, 1D, XCD-decoded in-kernel
    dim3 block(QPB * LPQ);
    EndPointSpline_kernel<<<grid, block, 0, stream>>>(query_t, knots, x0, x1, t, out);
}